// Round 3
// baseline (3296.889 us; speedup 1.0000x reference)
//
#include <hip/hip_runtime.h>
#include <stdint.h>

typedef _Float16 f16;
typedef _Float16 f16x8 __attribute__((ext_vector_type(8)));
typedef short bf16x8 __attribute__((ext_vector_type(8)));
typedef float f32x4 __attribute__((ext_vector_type(4)));

#define H_ 1024
#define NG_ 4096
#define F_ 512
#define B_ 64
#define T_ 128
#define CHUNK_ 16
#define NOP_ 640
#define NO_ 513

// Hamilton block structure: W[p-block(in)][q-block(out)] = sign * comp
__constant__ int c_comp[16] = {0,1,2,3, 1,0,3,2, 2,3,0,1, 3,2,1,0};
__constant__ float c_sgnf[16] = {1,1,1,1, -1,1,1,-1, -1,-1,1,1, -1,1,-1,1};

__device__ __forceinline__ float bf2f(unsigned short u){
  union { unsigned int i; float f; } v; v.i = ((unsigned int)u) << 16; return v.f;
}
__device__ __forceinline__ unsigned short f2bf(float f){
  union { float f; unsigned int i; } v; v.f = f;
  return (unsigned short)((v.i + 0x7fffu + ((v.i >> 16) & 1u)) >> 16);
}
// dual-path input load: flag=1 -> fp32 storage, flag=0 -> bf16 storage
__device__ __forceinline__ float ldin(const void* p, int i, int f){
  return f ? ((const float*)p)[i] : bf2f(((const unsigned short*)p)[i]);
}
__device__ __forceinline__ float sigm(float x){ return 1.f / (1.f + __expf(-x)); }
__device__ __forceinline__ float tanh_(float x){
  float ax = fabsf(x);
  float e = __expf(-2.f * ax);
  float t = (1.f - e) / (1.f + e);
  return x < 0.f ? -t : t;
}

// Detect input storage mode by sampling 256 even-index ushorts of x.
// fp32 raw values   -> even ushort = low mantissa half -> wild exponents
// fp32 bf16-rounded -> even ushort = exactly +/-0
// bf16 storage      -> sane exponents (x ~ N(0,1))
__global__ void detect_kernel(const unsigned short* __restrict__ xu, int* __restrict__ flag){
  __shared__ int zc, wc;
  if (threadIdx.x == 0){ zc = 0; wc = 0; }
  __syncthreads();
  unsigned short u = xu[2 * threadIdx.x];
  int e = (u >> 7) & 0xFF;
  bool z = (u & 0x7FFF) == 0;
  bool wild = !z && (e < 67 || e > 150);
  if (z) atomicAdd(&zc, 1);
  if (wild) atomicAdd(&wc, 1);
  __syncthreads();
  if (threadIdx.x == 0) *flag = (zc >= 128 || wc >= 64) ? 1 : 0;
}

#define XCHUNK_ELEMS (CHUNK_*B_*F_)   // 524288
__global__ void convert_x(const void* __restrict__ x, int elem_off,
                          const int* __restrict__ flag,
                          unsigned short* __restrict__ Xc){
  int f = *flag;
  int i = blockIdx.x * blockDim.x + threadIdx.x;
  int stride = gridDim.x * blockDim.x;
  for (; i < XCHUNK_ELEMS; i += stride) {
    int si = elem_off + i;
    Xc[i] = f ? f2bf(((const float*)x)[si]) : ((const unsigned short*)x)[si];
  }
}

#define WX_ELEMS (NG_*F_)
#define U_ELEMS  (NG_*H_)
#define FCO_ELEMS (NOP_*H_)
#define BIAS_ELEMS NG_
#define OB_ELEMS NOP_
#define PACK_TOTAL (WX_ELEMS + U_ELEMS + FCO_ELEMS + BIAS_ELEMS + OB_ELEMS)

__global__ void pack_kernel(
    const void* __restrict__ wf, const void* __restrict__ wi,
    const void* __restrict__ wo, const void* __restrict__ wc,
    const void* __restrict__ bfv, const void* __restrict__ biv,
    const void* __restrict__ bov, const void* __restrict__ bcv,
    const void* __restrict__ uf, const void* __restrict__ ui,
    const void* __restrict__ uo, const void* __restrict__ uc,
    const void* __restrict__ fcw, const void* __restrict__ fcb,
    const int* __restrict__ flag,
    unsigned short* __restrict__ Wx, f16* __restrict__ U, f16* __restrict__ Fco,
    float* __restrict__ bias, float* __restrict__ ob)
{
  const int fl = *flag;
  int i = blockIdx.x * blockDim.x + threadIdx.x;
  if (i < WX_ELEMS) {
    // Wx[n][k], n = g*1024 + q*256 + be, k = p*128 + al
    int n = i >> 9, k = i & 511;
    int g = n >> 10, nn = n & 1023;
    int q = nn >> 8, be = nn & 255;
    int p = k >> 7, al = k & 127;
    const void* w = (g==0) ? wf : (g==1) ? wi : (g==2) ? wo : wc;
    int pq = p*4 + q;
    Wx[i] = f2bf(c_sgnf[pq] * ldin(w, c_comp[pq]*32768 + al*256 + be, fl));
    return;
  }
  i -= WX_ELEMS;
  if (i < U_ELEMS) {
    // U[n][k], k = p*256 + al
    int n = i >> 10, k = i & 1023;
    int g = n >> 10;
    int q = (n & 1023) >> 8, be = n & 255;
    int p = k >> 8, al = k & 255;
    const void* u = (g==0) ? uf : (g==1) ? ui : (g==2) ? uo : uc;
    int pq = p*4 + q;
    U[i] = (f16)(c_sgnf[pq] * ldin(u, c_comp[pq]*65536 + al*256 + be, fl));
    return;
  }
  i -= U_ELEMS;
  if (i < FCO_ELEMS) {
    int n = i >> 10, k = i & 1023;
    Fco[i] = (n < NO_) ? (f16)ldin(fcw, k*NO_ + n, fl) : (f16)0.f;
    return;
  }
  i -= FCO_ELEMS;
  if (i < BIAS_ELEMS) {
    int g = i >> 10;
    const void* b = (g==0) ? bfv : (g==1) ? biv : (g==2) ? bov : bcv;
    bias[i] = ldin(b, i & 1023, fl);
    return;
  }
  i -= BIAS_ELEMS;
  if (i < OB_ELEMS) {
    ob[i] = (i < NO_) ? ldin(fcb, i, fl) : 0.f;
  }
}

// G = Xc @ Wx^T-layout : M=1024, N=4096, K=512, bf16 MFMA, f16 store
__global__ __launch_bounds__(256) void gemm_g(
    const unsigned short* __restrict__ X,
    const unsigned short* __restrict__ Wx,
    f16* __restrict__ G)
{
  const int lane = threadIdx.x & 63, w = threadIdx.x >> 6;
  const int lo = lane & 15, quad = lane >> 4;
  const int m0 = blockIdx.x * 128 + (w >> 1) * 64;
  const int n0 = blockIdx.y * 128 + (w & 1) * 64;
  f32x4 acc[4][4] = {};
  #pragma unroll 2
  for (int k0 = 0; k0 < F_; k0 += 32) {
    bf16x8 a[4], b[4];
    #pragma unroll
    for (int mt = 0; mt < 4; mt++)
      a[mt] = *(const bf16x8*)(X + (size_t)(m0 + 16*mt + lo) * F_ + k0 + quad*8);
    #pragma unroll
    for (int nt = 0; nt < 4; nt++)
      b[nt] = *(const bf16x8*)(Wx + (size_t)(n0 + 16*nt + lo) * F_ + k0 + quad*8);
    #pragma unroll
    for (int mt = 0; mt < 4; mt++)
      #pragma unroll
      for (int nt = 0; nt < 4; nt++)
        acc[mt][nt] = __builtin_amdgcn_mfma_f32_16x16x32_bf16(a[mt], b[nt], acc[mt][nt], 0, 0, 0);
  }
  #pragma unroll
  for (int mt = 0; mt < 4; mt++)
    #pragma unroll
    for (int nt = 0; nt < 4; nt++)
      #pragma unroll
      for (int r = 0; r < 4; r++) {
        int row = m0 + 16*mt + quad*4 + r;
        int col = n0 + 16*nt + lo;
        G[(size_t)row * NG_ + col] = (f16)acc[mt][nt][r];
      }
}

// One LSTM step. 64 blocks x 512 thr. Block owns 16 h-columns (all 4 gates).
__global__ __launch_bounds__(512) void step_kernel(
    const f16* __restrict__ Hprev, f16* __restrict__ Hnext,
    const f16* __restrict__ U, const f16* __restrict__ Gs,
    const float* __restrict__ bias, float* __restrict__ C)
{
  __shared__ float pre[2][4][64][16];
  const int tid = threadIdx.x;
  const int lane = tid & 63, w = tid >> 6;
  const int lo = lane & 15, quad = lane >> 4;
  const int g = w & 3, kh = w >> 2;
  const int jb = blockIdx.x * 16;
  const f16* Brow = U + (size_t)(g*H_ + jb + lo) * H_;
  f32x4 acc[4] = {};
  const int kbeg = kh * 512;
  #pragma unroll 4
  for (int ki = 0; ki < 16; ki++) {
    int k0 = kbeg + ki * 32;
    f16x8 bfrag = *(const f16x8*)(Brow + k0 + quad*8);
    #pragma unroll
    for (int mt = 0; mt < 4; mt++) {
      f16x8 afrag = *(const f16x8*)(Hprev + (size_t)(16*mt + lo) * H_ + k0 + quad*8);
      acc[mt] = __builtin_amdgcn_mfma_f32_16x16x32_f16(afrag, bfrag, acc[mt], 0, 0, 0);
    }
  }
  #pragma unroll
  for (int mt = 0; mt < 4; mt++)
    #pragma unroll
    for (int r = 0; r < 4; r++)
      pre[kh][g][16*mt + quad*4 + r][lo] = acc[mt][r];
  __syncthreads();
  #pragma unroll
  for (int rep = 0; rep < 2; rep++) {
    int p = tid + rep * 512;
    int b = p >> 4, jj = p & 15;
    int col = jb + jj;
    size_t gbase = (size_t)b * NG_ + col;
    float pf = pre[0][0][b][jj] + pre[1][0][b][jj] + (float)Gs[gbase]        + bias[col];
    float pi = pre[0][1][b][jj] + pre[1][1][b][jj] + (float)Gs[gbase + 1024] + bias[col + 1024];
    float po = pre[0][2][b][jj] + pre[1][2][b][jj] + (float)Gs[gbase + 2048] + bias[col + 2048];
    float pa = pre[0][3][b][jj] + pre[1][3][b][jj] + (float)Gs[gbase + 3072] + bias[col + 3072];
    float vf = sigm(pf), vi = sigm(pi), vo = sigm(po);
    float cold = C[(size_t)b * H_ + col];
    float cn = vi * tanh_(pa) + vf * cold;
    float hn = vo * tanh_(cn);
    C[(size_t)b * H_ + col] = cn;
    Hnext[(size_t)b * H_ + col] = (f16)hn;
  }
}

// out = Hall[1..128] @ Fco^T-layout + ob : M=8192, N=640(pad), K=1024, fp32 out
__global__ __launch_bounds__(256) void gemm_out(
    const f16* __restrict__ A,
    const f16* __restrict__ Bt,
    const float* __restrict__ ob,
    float* __restrict__ out)
{
  const int lane = threadIdx.x & 63, w = threadIdx.x >> 6;
  const int lo = lane & 15, quad = lane >> 4;
  const int m0 = blockIdx.x * 128 + (w >> 1) * 64;
  const int n0 = blockIdx.y * 128 + (w & 1) * 64;
  f32x4 acc[4][4] = {};
  #pragma unroll 2
  for (int k0 = 0; k0 < H_; k0 += 32) {
    f16x8 a[4], b[4];
    #pragma unroll
    for (int mt = 0; mt < 4; mt++)
      a[mt] = *(const f16x8*)(A + (size_t)(m0 + 16*mt + lo) * H_ + k0 + quad*8);
    #pragma unroll
    for (int nt = 0; nt < 4; nt++)
      b[nt] = *(const f16x8*)(Bt + (size_t)(n0 + 16*nt + lo) * H_ + k0 + quad*8);
    #pragma unroll
    for (int mt = 0; mt < 4; mt++)
      #pragma unroll
      for (int nt = 0; nt < 4; nt++)
        acc[mt][nt] = __builtin_amdgcn_mfma_f32_16x16x32_f16(a[mt], b[nt], acc[mt][nt], 0, 0, 0);
  }
  #pragma unroll
  for (int mt = 0; mt < 4; mt++)
    #pragma unroll
    for (int nt = 0; nt < 4; nt++)
      #pragma unroll
      for (int r = 0; r < 4; r++) {
        int row = m0 + 16*mt + quad*4 + r;
        int col = n0 + 16*nt + lo;
        if (col < NO_)
          out[(size_t)row * NO_ + col] = acc[mt][nt][r] + ob[col];
      }
}

extern "C" void kernel_launch(void* const* d_in, const int* in_sizes, int n_in,
                              void* d_out, int out_size, void* d_ws, size_t ws_size,
                              hipStream_t stream)
{
  const void* x   = d_in[0];
  const void* wfw = d_in[1];  const void* wfb = d_in[2];
  const void* wiw = d_in[3];  const void* wib = d_in[4];
  const void* wow = d_in[5];  const void* wob = d_in[6];
  const void* wcw = d_in[7];  const void* wcb = d_in[8];
  const void* ufw = d_in[9];  const void* uiw = d_in[10];
  const void* uow = d_in[11]; const void* ucw = d_in[12];
  const void* fcw = d_in[13]; const void* fcb = d_in[14];

  char* ws = (char*)d_ws;
  unsigned short* Wx = (unsigned short*)(ws + 0);        //  4,194,304 B
  f16*   U    = (f16*)  (ws + 4194304);                  //  8,388,608 B
  f16*   Fco  = (f16*)  (ws + 12582912);                 //  1,310,720 B
  f16*   G    = (f16*)  (ws + 13893632);                 //  8,388,608 B
  f16*   Hall = (f16*)  (ws + 22282240);                 // 16,908,288 B (129 states)
  float* C    = (float*)(ws + 39190528);                 //    262,144 B
  float* bias = (float*)(ws + 39452672);                 //     16,384 B
  float* ob   = (float*)(ws + 39469056);                 //      2,560 B
  unsigned short* Xc = (unsigned short*)(ws + 39471616); //  1,048,576 B
  int*   flag = (int*)  (ws + 40520192);                 //         16 B
  if (ws_size < 40520208u) return;

  hipMemsetAsync(Hall, 0, (size_t)B_*H_*sizeof(f16), stream);  // h_{-1} = 0
  hipMemsetAsync(C, 0, (size_t)B_*H_*sizeof(float), stream);   // c_{-1} = 0

  detect_kernel<<<1, 256, 0, stream>>>((const unsigned short*)x, flag);

  pack_kernel<<<(PACK_TOTAL + 255)/256, 256, 0, stream>>>(
      wfw, wiw, wow, wcw, wfb, wib, wob, wcb, ufw, uiw, uow, ucw, fcw, fcb,
      flag, Wx, U, Fco, bias, ob);

  for (int c = 0; c < T_/CHUNK_; c++) {
    convert_x<<<512, 256, 0, stream>>>(x, c * XCHUNK_ELEMS, flag, Xc);
    gemm_g<<<dim3(8, 32), 256, 0, stream>>>(Xc, Wx, G);
    for (int s = 0; s < CHUNK_; s++) {
      int t = c*CHUNK_ + s;
      step_kernel<<<64, 512, 0, stream>>>(
          Hall + (size_t)t*B_*H_, Hall + (size_t)(t+1)*B_*H_,
          U, G + (size_t)s*B_*NG_, bias, C);
    }
  }
  gemm_out<<<dim3(64, 5), 256, 0, stream>>>(Hall + (size_t)B_*H_, Fco, ob, (float*)d_out);
}